// Round 1
// baseline (152.353 us; speedup 1.0000x reference)
//
#include <hip/hip_runtime.h>

#define NSPEC  3
#define NMAXQ  8
#define NBASIS 8
#define EMBEDD 16
#define KMAX   32
#define RCUT   5.0f

// triu_indices(8) row-major
__constant__ int TUN[36] = {0,0,0,0,0,0,0,0, 1,1,1,1,1,1,1, 2,2,2,2,2,2, 3,3,3,3,3, 4,4,4,4, 5,5,5, 6,6, 7};
__constant__ int TUM[36] = {0,1,2,3,4,5,6,7, 1,2,3,4,5,6,7, 2,3,4,5,6,7, 3,4,5,6,7, 4,5,6,7, 5,6,7, 6,7, 7};

__global__ __launch_bounds__(64)
void magpot_kernel(const float* __restrict__ pos,
                   const int*   __restrict__ species,
                   const float* __restrict__ mag,
                   const int*   __restrict__ eidx,
                   const float* __restrict__ shifts,
                   const float* __restrict__ rb,
                   const float* __restrict__ semb,
                   const float* __restrict__ sshift,
                   const float* __restrict__ sscale,
                   const float* __restrict__ mshift,
                   const float* __restrict__ mscale,
                   const float* __restrict__ aes,
                   const float* __restrict__ wstruct,
                   const float* __restrict__ bstruct,
                   const float* __restrict__ wmag,
                   const float* __restrict__ bmag,
                   float* __restrict__ out,
                   int N, int E, int K)
{
    __shared__ float phi_s[KMAX * 8];
    __shared__ float rhat_s[KMAX * 3];
    __shared__ float mdj_s[KMAX * 3];
    __shared__ float uj_s[KMAX];
    __shared__ float t_s[KMAX * 8];
    __shared__ float P_s[8 * 3];
    __shared__ float Q_s[8 * 6];   // xx,xy,xz,yy,yz,zz (traceless symmetric)
    __shared__ float M_s[8 * 3];
    __shared__ float W_s[8 * 3];
    __shared__ float mQ_s[8 * 3];
    __shared__ float ds_s[80];
    __shared__ float dm_s[251];

    const int i = blockIdx.x;
    if (i >= N) return;
    const int lane = threadIdx.x;

    // ---- atom-level quantities (broadcast loads, all lanes) ----
    const float pix = pos[3*i+0], piy = pos[3*i+1], piz = pos[3*i+2];
    const int   spi = species[i];
    const float mgx = mag[3*i+0], mgy = mag[3*i+1], mgz = mag[3*i+2];
    const float u_i = mgx*mgx + mgy*mgy + mgz*mgz;
    const float mn_i = sqrtf(u_i);
    const float mi_inv = (mn_i > 1e-8f) ? (1.0f / mn_i) : 0.0f;
    const float mix = mgx*mi_inv, miy = mgy*mi_inv, miz = mgz*mi_inv;

    // ---- phase 1: per-edge (lanes 0..K-1), keep phi/r in registers for the scan ----
    float phi[8];
    float rx = 0.0f, ry = 0.0f, rz = 0.0f;
    #pragma unroll
    for (int n = 0; n < 8; ++n) phi[n] = 0.0f;

    if (lane < KMAX) {
        if (lane < K) {
            const int e = i * K + lane;
            const int j = eidx[E + e];
            rx = pos[3*j+0] - pix + shifts[3*e+0];
            ry = pos[3*j+1] - piy + shifts[3*e+1];
            rz = pos[3*j+2] - piz + shifts[3*e+2];
            const float dist = sqrtf(rx*rx + ry*ry + rz*rz);
            const float fc = (dist < RCUT)
                ? (0.5f * cosf(3.14159265358979323846f * dist * (1.0f/RCUT)) + 0.5f)
                : 0.0f;
            const float xr = dist * (1.0f/RCUT);
            const float x  = 2.0f * xr * xr - 1.0f;
            float f[8];
            {
                float Tm2 = 1.0f, Tm1 = x;
                f[0] = 0.5f * (Tm2 + 1.0f) * fc;
                f[1] = 0.5f * (Tm1 + 1.0f) * fc;
                #pragma unroll
                for (int k = 2; k < 8; ++k) {
                    const float T = 2.0f * x * Tm1 - Tm2;
                    Tm2 = Tm1; Tm1 = T;
                    f[k] = 0.5f * (T + 1.0f) * fc;
                }
            }
            const int spj = species[j];
            const float* rbp = rb + (spi * NSPEC + spj) * (NMAXQ * NBASIS);
            #pragma unroll
            for (int n = 0; n < 8; ++n) {
                float s = 0.0f;
                #pragma unroll
                for (int k = 0; k < 8; ++k) s += rbp[n*8 + k] * f[k];
                phi[n] = s;
                phi_s[lane*8 + n] = s;
            }
            const float dinv = 1.0f / fmaxf(dist, 1e-8f);
            rhat_s[lane*3+0] = rx * dinv;
            rhat_s[lane*3+1] = ry * dinv;
            rhat_s[lane*3+2] = rz * dinv;
            const float mjx = mag[3*j+0], mjy = mag[3*j+1], mjz = mag[3*j+2];
            const float uj = mjx*mjx + mjy*mjy + mjz*mjz;
            const float mnj = sqrtf(uj);
            const float mjinv = (mnj > 1e-8f) ? (1.0f / mnj) : 0.0f;
            mdj_s[lane*3+0] = mjx * mjinv;
            mdj_s[lane*3+1] = mjy * mjinv;
            mdj_s[lane*3+2] = mjz * mjinv;
            uj_s[lane] = uj;
        } else {
            #pragma unroll
            for (int n = 0; n < 8; ++n) phi_s[lane*8 + n] = 0.0f;
            rhat_s[lane*3+0] = 0.0f; rhat_s[lane*3+1] = 0.0f; rhat_s[lane*3+2] = 0.0f;
            mdj_s[lane*3+0] = 0.0f; mdj_s[lane*3+1] = 0.0f; mdj_s[lane*3+2] = 0.0f;
            uj_s[lane] = 0.0f;
        }
    }
    __syncthreads();

    // ---- phase 2: segment sums. lane = (k8, n); each lane does 4 edges, xor-reduce over k8 ----
    {
        const int k8 = lane >> 3;
        const int n  = lane & 7;
        float a_dr = 0.0f;
        float aP0 = 0.0f, aP1 = 0.0f, aP2 = 0.0f;
        float aQ0 = 0.0f, aQ1 = 0.0f, aQ2 = 0.0f, aQ3 = 0.0f, aQ4 = 0.0f, aQ5 = 0.0f;
        float aM0 = 0.0f, aM1 = 0.0f, aM2 = 0.0f;
        float a_nb = 0.0f;
        float aW0 = 0.0f, aW1 = 0.0f, aW2 = 0.0f;
        #pragma unroll
        for (int c = 0; c < 4; ++c) {
            const int e = k8 + 8*c;
            const float ph = phi_s[e*8 + n];
            const float hx = rhat_s[e*3+0], hy = rhat_s[e*3+1], hz = rhat_s[e*3+2];
            const float dx = mdj_s[e*3+0], dy = mdj_s[e*3+1], dz = mdj_s[e*3+2];
            const float uj = uj_s[e];
            a_dr += ph;
            aP0 += ph*hx; aP1 += ph*hy; aP2 += ph*hz;
            aQ0 += ph*(hx*hx - (1.0f/3.0f));
            aQ1 += ph*(hx*hy);
            aQ2 += ph*(hx*hz);
            aQ3 += ph*(hy*hy - (1.0f/3.0f));
            aQ4 += ph*(hy*hz);
            aQ5 += ph*(hz*hz - (1.0f/3.0f));
            aM0 += ph*dx; aM1 += ph*dy; aM2 += ph*dz;
            a_nb += ph*uj;
            const float pu = ph*uj;
            aW0 += pu*dx; aW1 += pu*dy; aW2 += pu*dz;
        }
        #pragma unroll
        for (int d = 8; d <= 32; d <<= 1) {
            a_dr += __shfl_xor(a_dr, d, 64);
            aP0 += __shfl_xor(aP0, d, 64); aP1 += __shfl_xor(aP1, d, 64); aP2 += __shfl_xor(aP2, d, 64);
            aQ0 += __shfl_xor(aQ0, d, 64); aQ1 += __shfl_xor(aQ1, d, 64); aQ2 += __shfl_xor(aQ2, d, 64);
            aQ3 += __shfl_xor(aQ3, d, 64); aQ4 += __shfl_xor(aQ4, d, 64); aQ5 += __shfl_xor(aQ5, d, 64);
            aM0 += __shfl_xor(aM0, d, 64); aM1 += __shfl_xor(aM1, d, 64); aM2 += __shfl_xor(aM2, d, 64);
            a_nb += __shfl_xor(a_nb, d, 64);
            aW0 += __shfl_xor(aW0, d, 64); aW1 += __shfl_xor(aW1, d, 64); aW2 += __shfl_xor(aW2, d, 64);
        }
        if (k8 == 0) {
            P_s[n*3+0] = aP0; P_s[n*3+1] = aP1; P_s[n*3+2] = aP2;
            Q_s[n*6+0] = aQ0; Q_s[n*6+1] = aQ1; Q_s[n*6+2] = aQ2;
            Q_s[n*6+3] = aQ3; Q_s[n*6+4] = aQ4; Q_s[n*6+5] = aQ5;
            M_s[n*3+0] = aM0; M_s[n*3+1] = aM1; M_s[n*3+2] = aM2;
            W_s[n*3+0] = aW0; W_s[n*3+1] = aW1; W_s[n*3+2] = aW2;
            ds_s[n] = a_dr;          // d_radial
            dm_s[227 + n] = a_nb;    // d_nbr_amp
        }
    }
    __syncthreads();

    // ---- phase 3a: DMI suffix scan. S_a[m] = sum_{b>a} phi_b[m] r_b via shfl_down scan ----
    {
        float S[8][3];
        #pragma unroll
        for (int m = 0; m < 8; ++m) {
            S[m][0] = phi[m] * rx;   // lanes >= K hold zeros (phi=0, r=0)
            S[m][1] = phi[m] * ry;
            S[m][2] = phi[m] * rz;
        }
        #pragma unroll
        for (int d = 1; d <= 16; d <<= 1) {
            #pragma unroll
            for (int m = 0; m < 8; ++m) {
                S[m][0] += __shfl_down(S[m][0], d, 64);
                S[m][1] += __shfl_down(S[m][1], d, 64);
                S[m][2] += __shfl_down(S[m][2], d, 64);
            }
        }
        #pragma unroll
        for (int m = 0; m < 8; ++m) {
            const float Sx = S[m][0] - phi[m]*rx;   // exclusive (b > a)
            const float Sy = S[m][1] - phi[m]*ry;
            const float Sz = S[m][2] - phi[m]*rz;
            const float Mx = M_s[m*3+0], My = M_s[m*3+1], Mz = M_s[m*3+2];
            // mcM[m] = m_dir_i x M[m]
            const float wx = miy*Mz - miz*My;
            const float wy = miz*Mx - mix*Mz;
            const float wz = mix*My - miy*Mx;
            // (r_a x S) . mcM
            const float cx = ry*Sz - rz*Sy;
            const float cy = rz*Sx - rx*Sz;
            const float cz = rx*Sy - ry*Sx;
            const float tm = cx*wx + cy*wy + cz*wz;
            if (lane < KMAX) t_s[lane*8 + m] = tm;
        }
    }
    __syncthreads();

    // ---- phase 3b: d_dmi[n][m] = sum_a phi_a[n] * t_a[m]; lane = n*8+m ----
    {
        const int n3 = lane >> 3, m3 = lane & 7;
        float dmi = 0.0f;
        #pragma unroll 8
        for (int a = 0; a < KMAX; ++a)
            dmi += phi_s[a*8 + n3] * t_s[a*8 + m3];
        dm_s[83 + lane]  = dmi;         // d_dmi
        dm_s[163 + lane] = u_i * dmi;   // u * d_dmi (inside d_amp_mix)
    }

    // ---- phase 4a: per-n magnetic descriptors (lanes 0..7) ----
    if (lane < 8) {
        const int n = lane;
        const float Mx = M_s[n*3+0], My = M_s[n*3+1], Mz = M_s[n*3+2];
        const float diso = mix*Mx + miy*My + miz*Mz;
        dm_s[3 + n]   = diso;
        dm_s[147 + n] = u_i * diso;
        const float q0 = Q_s[n*6+0], q1 = Q_s[n*6+1], q2 = Q_s[n*6+2];
        const float q3 = Q_s[n*6+3], q4 = Q_s[n*6+4], q5 = Q_s[n*6+5];
        const float dsia = q0*mix*mix + q3*miy*miy + q5*miz*miz
                         + 2.0f*(q1*mix*miy + q2*mix*miz + q4*miy*miz);
        dm_s[11 + n]  = dsia;
        dm_s[155 + n] = u_i * dsia;
        mQ_s[n*3+0] = q0*mix + q1*miy + q2*miz;
        mQ_s[n*3+1] = q1*mix + q3*miy + q4*miz;
        mQ_s[n*3+2] = q2*mix + q4*miy + q5*miz;
        const float wx = W_s[n*3+0], wy = W_s[n*3+1], wz = W_s[n*3+2];
        const float dnex = mix*wx + miy*wy + miz*wz;
        dm_s[235 + n] = dnex;
        dm_s[243 + n] = u_i * dnex;
    }
    if (lane == 0) {
        dm_s[0] = u_i;
        dm_s[1] = u_i * u_i;
        dm_s[2] = u_i * u_i * u_i;
    }
    __syncthreads();

    // ---- phase 4b: d_sae (64, lane = m*8+n) + PP/QQ upper triangles (lanes 0..35) ----
    {
        const int m4 = lane >> 3, n4 = lane & 7;
        dm_s[19 + lane] = mQ_s[m4*3+0]*M_s[n4*3+0]
                        + mQ_s[m4*3+1]*M_s[n4*3+1]
                        + mQ_s[m4*3+2]*M_s[n4*3+2];
        if (lane < 36) {
            const int a = TUN[lane], b = TUM[lane];
            ds_s[8 + lane] = P_s[a*3+0]*P_s[b*3+0] + P_s[a*3+1]*P_s[b*3+1] + P_s[a*3+2]*P_s[b*3+2];
            ds_s[44 + lane] = Q_s[a*6+0]*Q_s[b*6+0] + Q_s[a*6+3]*Q_s[b*6+3] + Q_s[a*6+5]*Q_s[b*6+5]
                  + 2.0f*(Q_s[a*6+1]*Q_s[b*6+1] + Q_s[a*6+2]*Q_s[b*6+2] + Q_s[a*6+4]*Q_s[b*6+4]);
        }
    }
    __syncthreads();

    // ---- phase 5: normalized dot with weights, wave reduction ----
    float p = 0.0f;
    #pragma unroll
    for (int t = lane; t < 80; t += 64)
        p += wstruct[16 + t] * (ds_s[t] - sshift[t]) / sscale[t];
    #pragma unroll
    for (int t = lane; t < 251; t += 64)
        p += wmag[16 + t] * (dm_s[t] - mshift[t]) / mscale[t];
    if (lane < EMBEDD)
        p += semb[spi*EMBEDD + lane] * (wstruct[lane] + wmag[lane]);
    #pragma unroll
    for (int d = 1; d <= 32; d <<= 1)
        p += __shfl_xor(p, d, 64);
    if (lane == 0)
        out[i] = p + bstruct[0] + bmag[0] + aes[spi];
}

extern "C" void kernel_launch(void* const* d_in, const int* in_sizes, int n_in,
                              void* d_out, int out_size, void* d_ws, size_t ws_size,
                              hipStream_t stream) {
    const float* pos     = (const float*)d_in[0];
    const int*   spc     = (const int*)  d_in[1];
    const float* mg      = (const float*)d_in[2];
    const int*   eidx    = (const int*)  d_in[3];
    const float* shf     = (const float*)d_in[4];
    const float* rb      = (const float*)d_in[5];
    const float* semb    = (const float*)d_in[6];
    const float* sshift  = (const float*)d_in[7];
    const float* sscale  = (const float*)d_in[8];
    const float* mshift  = (const float*)d_in[9];
    const float* mscale  = (const float*)d_in[10];
    const float* aes     = (const float*)d_in[11];
    const float* wstruct = (const float*)d_in[12];
    const float* bstruct = (const float*)d_in[13];
    const float* wmag    = (const float*)d_in[14];
    const float* bmag    = (const float*)d_in[15];
    float* out = (float*)d_out;

    const int N = in_sizes[1];
    const int E = in_sizes[3] / 2;
    const int K = E / N;

    hipLaunchKernelGGL(magpot_kernel, dim3(N), dim3(64), 0, stream,
                       pos, spc, mg, eidx, shf, rb, semb, sshift, sscale,
                       mshift, mscale, aes, wstruct, bstruct, wmag, bmag,
                       out, N, E, K);
}

// Round 2
// 133.116 us; speedup vs baseline: 1.1445x; 1.1445x over previous
//
#include <hip/hip_runtime.h>

#define NSPEC  3
#define EMBEDD 16
#define KMAX   32
#define RCUT   5.0f
#define PADR   36   // padded row stride (floats) for phiT/tT: 16B-aligned rows, decorrelated banks

// triu_indices(8) row-major
__constant__ int TUN[36] = {0,0,0,0,0,0,0,0, 1,1,1,1,1,1,1, 2,2,2,2,2,2, 3,3,3,3,3, 4,4,4,4, 5,5,5, 6,6, 7};
__constant__ int TUM[36] = {0,1,2,3,4,5,6,7, 1,2,3,4,5,6,7, 2,3,4,5,6,7, 3,4,5,6,7, 4,5,6,7, 5,6,7, 6,7, 7};

// ws layout (precomputed by magpot_setup into d_ws):
//   [0..79]    wstruct[16+t]/sscale[t]
//   [80..330]  wmag[16+t]/mscale[t]
//   [331]      bstruct+bmag - sum_t w*shift/scale   (atom-independent)
//   [332..347] wstruct[l]+wmag[l]  (embedding weights)

struct __align__(16) AtomLds {
    float phiT[8 * PADR];            // phiT[n*PADR + a]
    float tT[8 * PADR];              // tT[m*PADR + a]
    float rhx[KMAX], rhy[KMAX], rhz[KMAX];
    float mdx[KMAX], mdy[KMAX], mdz[KMAX];
    float uj[KMAX];
    float P[24], Q[48], M[24], W[24], mQ[24];
};  // 944 floats = 3776 B

__global__ __launch_bounds__(256)
void magpot_setup(const float* __restrict__ sshift, const float* __restrict__ sscale,
                  const float* __restrict__ mshift, const float* __restrict__ mscale,
                  const float* __restrict__ wstruct, const float* __restrict__ bstruct,
                  const float* __restrict__ wmag, const float* __restrict__ bmag,
                  float* __restrict__ ws)
{
    __shared__ float red[4];
    const int t = threadIdx.x;
    float c = 0.0f;
    for (int idx = t; idx < 80; idx += 256) {
        const float w = wstruct[16 + idx] / sscale[idx];
        ws[idx] = w;
        c += w * sshift[idx];
    }
    for (int idx = t; idx < 251; idx += 256) {
        const float w = wmag[16 + idx] / mscale[idx];
        ws[80 + idx] = w;
        c += w * mshift[idx];
    }
    if (t < EMBEDD) ws[332 + t] = wstruct[t] + wmag[t];
    #pragma unroll
    for (int d = 1; d <= 32; d <<= 1) c += __shfl_xor(c, d, 64);
    if ((t & 63) == 0) red[t >> 6] = c;
    __syncthreads();
    if (t == 0) ws[331] = bstruct[0] + bmag[0] - (red[0] + red[1] + red[2] + red[3]);
}

__global__ __launch_bounds__(256, 5)
void magpot_main(const float* __restrict__ pos,
                 const int*   __restrict__ species,
                 const float* __restrict__ mag,
                 const int*   __restrict__ eidx,
                 const float* __restrict__ shifts,
                 const float* __restrict__ rb,
                 const float* __restrict__ semb,
                 const float* __restrict__ aes,
                 const float* __restrict__ ws,
                 float* __restrict__ out,
                 int N, int E, int K)
{
    __shared__ AtomLds lds[8];

    const int lane64 = threadIdx.x & 63;
    const int wv     = threadIdx.x >> 6;   // wave in block (0..3)
    const int h      = lane64 >> 5;        // half (atom within wave)
    const int s      = lane64 & 31;        // sub-lane within half
    const int i      = blockIdx.x * 8 + wv * 2 + h;
    const bool valid = (i < N);
    const int isafe  = valid ? i : 0;
    AtomLds& L = lds[wv * 2 + h];

    const float* wm = ws + 80;

    // ---- atom-level quantities (broadcast within each half) ----
    const float pix = pos[3*isafe+0], piy = pos[3*isafe+1], piz = pos[3*isafe+2];
    const int   spi = species[isafe];
    const float mgx = mag[3*isafe+0], mgy = mag[3*isafe+1], mgz = mag[3*isafe+2];
    const float u_i = mgx*mgx + mgy*mgy + mgz*mgz;
    const float mn_i = sqrtf(u_i);
    const float mi_inv = (mn_i > 1e-8f) ? (1.0f / mn_i) : 0.0f;
    const float mix = mgx*mi_inv, miy = mgy*mi_inv, miz = mgz*mi_inv;

    // ---- phase 1: per-edge, all 64 lanes (edge s of atom i) ----
    float phi[8];
    float rx = 0.0f, ry = 0.0f, rz = 0.0f;
    #pragma unroll
    for (int n = 0; n < 8; ++n) phi[n] = 0.0f;

    if (s < K) {
        const int e = isafe * K + s;
        const int j = eidx[E + e];
        rx = pos[3*j+0] - pix + shifts[3*e+0];
        ry = pos[3*j+1] - piy + shifts[3*e+1];
        rz = pos[3*j+2] - piz + shifts[3*e+2];
        const float dist = sqrtf(rx*rx + ry*ry + rz*rz);
        const float fc = (dist < RCUT)
            ? (0.5f * cosf(3.14159265358979323846f * dist * (1.0f/RCUT)) + 0.5f)
            : 0.0f;
        const float xr = dist * (1.0f/RCUT);
        const float x  = 2.0f * xr * xr - 1.0f;
        float f[8];
        {
            float Tm2 = 1.0f, Tm1 = x;
            f[0] = 0.5f * (Tm2 + 1.0f) * fc;
            f[1] = 0.5f * (Tm1 + 1.0f) * fc;
            #pragma unroll
            for (int k = 2; k < 8; ++k) {
                const float T = 2.0f * x * Tm1 - Tm2;
                Tm2 = Tm1; Tm1 = T;
                f[k] = 0.5f * (T + 1.0f) * fc;
            }
        }
        const int spj = species[j];
        const float4* rb4 = (const float4*)(rb + (spi * NSPEC + spj) * 64);
        #pragma unroll
        for (int n = 0; n < 8; ++n) {
            const float4 r0 = rb4[n*2+0];
            const float4 r1 = rb4[n*2+1];
            const float ph = r0.x*f[0] + r0.y*f[1] + r0.z*f[2] + r0.w*f[3]
                           + r1.x*f[4] + r1.y*f[5] + r1.z*f[6] + r1.w*f[7];
            phi[n] = ph;
            L.phiT[n*PADR + s] = ph;
        }
        const float dinv = 1.0f / fmaxf(dist, 1e-8f);
        L.rhx[s] = rx * dinv;
        L.rhy[s] = ry * dinv;
        L.rhz[s] = rz * dinv;
        const float mjx = mag[3*j+0], mjy = mag[3*j+1], mjz = mag[3*j+2];
        const float uj = mjx*mjx + mjy*mjy + mjz*mjz;
        const float mnj = sqrtf(uj);
        const float mjinv = (mnj > 1e-8f) ? (1.0f / mnj) : 0.0f;
        L.mdx[s] = mjx * mjinv;
        L.mdy[s] = mjy * mjinv;
        L.mdz[s] = mjz * mjinv;
        L.uj[s] = uj;
    } else {
        #pragma unroll
        for (int n = 0; n < 8; ++n) L.phiT[n*PADR + s] = 0.0f;
        L.rhx[s] = 0.0f; L.rhy[s] = 0.0f; L.rhz[s] = 0.0f;
        L.mdx[s] = 0.0f; L.mdy[s] = 0.0f; L.mdz[s] = 0.0f;
        L.uj[s] = 0.0f;
    }
    __syncthreads();

    float p = 0.0f;   // fused weighted-descriptor accumulator (reduced per half at end)

    // ---- phase 2: segment sums. s = k4*8+n; each lane does 8 contiguous edges, xor-reduce over k4 ----
    {
        const int k4 = s >> 3;
        const int n  = s & 7;
        const float4* phR = (const float4*)&L.phiT[n*PADR + k4*8];
        const float4* hxR = (const float4*)&L.rhx[k4*8];
        const float4* hyR = (const float4*)&L.rhy[k4*8];
        const float4* hzR = (const float4*)&L.rhz[k4*8];
        const float4* dxR = (const float4*)&L.mdx[k4*8];
        const float4* dyR = (const float4*)&L.mdy[k4*8];
        const float4* dzR = (const float4*)&L.mdz[k4*8];
        const float4* ujR = (const float4*)&L.uj[k4*8];

        float a_dr = 0.0f;
        float aP0 = 0.0f, aP1 = 0.0f, aP2 = 0.0f;
        float aQ0 = 0.0f, aQ1 = 0.0f, aQ2 = 0.0f, aQ3 = 0.0f, aQ4 = 0.0f, aQ5 = 0.0f;
        float aM0 = 0.0f, aM1 = 0.0f, aM2 = 0.0f;
        float a_nb = 0.0f;
        float aW0 = 0.0f, aW1 = 0.0f, aW2 = 0.0f;

        auto acc = [&](float ph, float hx, float hy, float hz,
                       float dx, float dy, float dz, float uj) {
            a_dr += ph;
            aP0 += ph*hx; aP1 += ph*hy; aP2 += ph*hz;
            aQ0 += ph*(hx*hx - (1.0f/3.0f));
            aQ1 += ph*(hx*hy);
            aQ2 += ph*(hx*hz);
            aQ3 += ph*(hy*hy - (1.0f/3.0f));
            aQ4 += ph*(hy*hz);
            aQ5 += ph*(hz*hz - (1.0f/3.0f));
            aM0 += ph*dx; aM1 += ph*dy; aM2 += ph*dz;
            const float pu = ph*uj;
            a_nb += pu;
            aW0 += pu*dx; aW1 += pu*dy; aW2 += pu*dz;
        };
        #pragma unroll
        for (int q = 0; q < 2; ++q) {
            const float4 ph4 = phR[q], hx4 = hxR[q], hy4 = hyR[q], hz4 = hzR[q];
            const float4 dx4 = dxR[q], dy4 = dyR[q], dz4 = dzR[q], uj4 = ujR[q];
            acc(ph4.x, hx4.x, hy4.x, hz4.x, dx4.x, dy4.x, dz4.x, uj4.x);
            acc(ph4.y, hx4.y, hy4.y, hz4.y, dx4.y, dy4.y, dz4.y, uj4.y);
            acc(ph4.z, hx4.z, hy4.z, hz4.z, dx4.z, dy4.z, dz4.z, uj4.z);
            acc(ph4.w, hx4.w, hy4.w, hz4.w, dx4.w, dy4.w, dz4.w, uj4.w);
        }
        #pragma unroll
        for (int d = 8; d <= 16; d <<= 1) {
            a_dr += __shfl_xor(a_dr, d, 64);
            aP0 += __shfl_xor(aP0, d, 64); aP1 += __shfl_xor(aP1, d, 64); aP2 += __shfl_xor(aP2, d, 64);
            aQ0 += __shfl_xor(aQ0, d, 64); aQ1 += __shfl_xor(aQ1, d, 64); aQ2 += __shfl_xor(aQ2, d, 64);
            aQ3 += __shfl_xor(aQ3, d, 64); aQ4 += __shfl_xor(aQ4, d, 64); aQ5 += __shfl_xor(aQ5, d, 64);
            aM0 += __shfl_xor(aM0, d, 64); aM1 += __shfl_xor(aM1, d, 64); aM2 += __shfl_xor(aM2, d, 64);
            a_nb += __shfl_xor(a_nb, d, 64);
            aW0 += __shfl_xor(aW0, d, 64); aW1 += __shfl_xor(aW1, d, 64); aW2 += __shfl_xor(aW2, d, 64);
        }
        if (k4 == 0) {
            L.P[n*3+0] = aP0; L.P[n*3+1] = aP1; L.P[n*3+2] = aP2;
            L.Q[n*6+0] = aQ0; L.Q[n*6+1] = aQ1; L.Q[n*6+2] = aQ2;
            L.Q[n*6+3] = aQ3; L.Q[n*6+4] = aQ4; L.Q[n*6+5] = aQ5;
            L.M[n*3+0] = aM0; L.M[n*3+1] = aM1; L.M[n*3+2] = aM2;
            L.W[n*3+0] = aW0; L.W[n*3+1] = aW1; L.W[n*3+2] = aW2;
            p += a_dr * ws[n];          // d_radial
            p += a_nb * wm[227 + n];    // d_nbr_amp
        }
        if (s == 8) {                   // d_amp (one lane per atom)
            const float u2 = u_i * u_i;
            p += u_i * wm[0] + u2 * wm[1] + u2 * u_i * wm[2];
        }
        if (s < EMBEDD)                 // embedding term
            p += semb[spi * EMBEDD + s] * ws[332 + s];
    }
    __syncthreads();

    // ---- phase 3a: DMI suffix scan within each 32-half ----
    {
        float S[8][3];
        #pragma unroll
        for (int m = 0; m < 8; ++m) {
            S[m][0] = phi[m] * rx;
            S[m][1] = phi[m] * ry;
            S[m][2] = phi[m] * rz;
        }
        #pragma unroll
        for (int d = 1; d <= 16; d <<= 1) {
            const bool ok = (s + d) < 32;   // don't pull from the other half
            #pragma unroll
            for (int m = 0; m < 8; ++m) {
                const float v0 = __shfl_down(S[m][0], d, 64);
                const float v1 = __shfl_down(S[m][1], d, 64);
                const float v2 = __shfl_down(S[m][2], d, 64);
                S[m][0] += ok ? v0 : 0.0f;
                S[m][1] += ok ? v1 : 0.0f;
                S[m][2] += ok ? v2 : 0.0f;
            }
        }
        #pragma unroll
        for (int m = 0; m < 8; ++m) {
            const float Sx = S[m][0] - phi[m]*rx;   // exclusive (b > a)
            const float Sy = S[m][1] - phi[m]*ry;
            const float Sz = S[m][2] - phi[m]*rz;
            const float Mx = L.M[m*3+0], My = L.M[m*3+1], Mz = L.M[m*3+2];
            const float wx = miy*Mz - miz*My;       // m_i x M[m]
            const float wy = miz*Mx - mix*Mz;
            const float wz = mix*My - miy*Mx;
            const float cx = ry*Sz - rz*Sy;         // r_a x S
            const float cy = rz*Sx - rx*Sz;
            const float cz = rx*Sy - ry*Sx;
            L.tT[m*PADR + s] = cx*wx + cy*wy + cz*wz;
        }
    }
    __syncthreads();

    // ---- phase 3b: d_dmi[n][m] = sum_a phiT[n][a] * tT[m][a]; lane does pairs (n, 2c) (n, 2c+1) ----
    {
        const int n  = s >> 2;
        const int mb = (s & 3) << 1;
        const float4* phR = (const float4*)&L.phiT[n*PADR];
        const float4* t0R = (const float4*)&L.tT[mb*PADR];
        const float4* t1R = (const float4*)&L.tT[(mb+1)*PADR];
        float d0 = 0.0f, d1 = 0.0f;
        #pragma unroll
        for (int q = 0; q < 8; ++q) {
            const float4 pv = phR[q];
            const float4 t0 = t0R[q];
            const float4 t1 = t1R[q];
            d0 += pv.x*t0.x + pv.y*t0.y + pv.z*t0.z + pv.w*t0.w;
            d1 += pv.x*t1.x + pv.y*t1.y + pv.z*t1.z + pv.w*t1.w;
        }
        const int i0 = n*8 + mb;
        p += d0 * wm[83 + i0]     + (u_i * d0) * wm[163 + i0];
        p += d1 * wm[83 + i0 + 1] + (u_i * d1) * wm[163 + i0 + 1];
    }

    // ---- phase 4a: per-n magnetic descriptors (lanes s<8) ----
    if (s < 8) {
        const int n = s;
        const float Mx = L.M[n*3+0], My = L.M[n*3+1], Mz = L.M[n*3+2];
        const float diso = mix*Mx + miy*My + miz*Mz;
        const float q0 = L.Q[n*6+0], q1 = L.Q[n*6+1], q2 = L.Q[n*6+2];
        const float q3 = L.Q[n*6+3], q4 = L.Q[n*6+4], q5 = L.Q[n*6+5];
        const float dsia = q0*mix*mix + q3*miy*miy + q5*miz*miz
                         + 2.0f*(q1*mix*miy + q2*mix*miz + q4*miy*miz);
        L.mQ[n*3+0] = q0*mix + q1*miy + q2*miz;
        L.mQ[n*3+1] = q1*mix + q3*miy + q4*miz;
        L.mQ[n*3+2] = q2*mix + q4*miy + q5*miz;
        const float wx = L.W[n*3+0], wy = L.W[n*3+1], wz = L.W[n*3+2];
        const float dnex = mix*wx + miy*wy + miz*wz;
        p += diso * wm[3 + n]  + dsia * wm[11 + n]  + dnex * wm[235 + n]
           + u_i * (diso * wm[147 + n] + dsia * wm[155 + n] + dnex * wm[243 + n]);
    }
    __syncthreads();

    // ---- phase 4b: d_sae (64) + PP/QQ upper triangles (36 each) ----
    {
        #pragma unroll
        for (int t2 = 0; t2 < 2; ++t2) {
            const int idx = s + t2*32;
            const int m4 = idx >> 3, n4 = idx & 7;
            const float sae = L.mQ[m4*3+0]*L.M[n4*3+0]
                            + L.mQ[m4*3+1]*L.M[n4*3+1]
                            + L.mQ[m4*3+2]*L.M[n4*3+2];
            p += sae * wm[19 + idx];
        }
        #pragma unroll
        for (int t2 = 0; t2 < 2; ++t2) {
            const int idx = s + t2*32;
            if (idx < 36) {
                const int a = TUN[idx], b = TUM[idx];
                const float pp = L.P[a*3+0]*L.P[b*3+0] + L.P[a*3+1]*L.P[b*3+1] + L.P[a*3+2]*L.P[b*3+2];
                const float qq = L.Q[a*6+0]*L.Q[b*6+0] + L.Q[a*6+3]*L.Q[b*6+3] + L.Q[a*6+5]*L.Q[b*6+5]
                       + 2.0f*(L.Q[a*6+1]*L.Q[b*6+1] + L.Q[a*6+2]*L.Q[b*6+2] + L.Q[a*6+4]*L.Q[b*6+4]);
                p += pp * ws[8 + idx] + qq * ws[44 + idx];
            }
        }
    }

    // ---- final: reduce p within each 32-half, lane 0 writes ----
    #pragma unroll
    for (int d = 1; d <= 16; d <<= 1) p += __shfl_xor(p, d, 64);
    if (s == 0 && valid)
        out[i] = p + ws[331] + aes[spi];
}

extern "C" void kernel_launch(void* const* d_in, const int* in_sizes, int n_in,
                              void* d_out, int out_size, void* d_ws, size_t ws_size,
                              hipStream_t stream) {
    const float* pos     = (const float*)d_in[0];
    const int*   spc     = (const int*)  d_in[1];
    const float* mg      = (const float*)d_in[2];
    const int*   eidx    = (const int*)  d_in[3];
    const float* shf     = (const float*)d_in[4];
    const float* rb      = (const float*)d_in[5];
    const float* semb    = (const float*)d_in[6];
    const float* sshift  = (const float*)d_in[7];
    const float* sscale  = (const float*)d_in[8];
    const float* mshift  = (const float*)d_in[9];
    const float* mscale  = (const float*)d_in[10];
    const float* aes     = (const float*)d_in[11];
    const float* wstruct = (const float*)d_in[12];
    const float* bstruct = (const float*)d_in[13];
    const float* wmag    = (const float*)d_in[14];
    const float* bmag    = (const float*)d_in[15];
    float* out = (float*)d_out;
    float* ws  = (float*)d_ws;

    const int N = in_sizes[1];
    const int E = in_sizes[3] / 2;
    const int K = E / N;

    hipLaunchKernelGGL(magpot_setup, dim3(1), dim3(256), 0, stream,
                       sshift, sscale, mshift, mscale, wstruct, bstruct, wmag, bmag, ws);
    hipLaunchKernelGGL(magpot_main, dim3((N + 7) / 8), dim3(256), 0, stream,
                       pos, spc, mg, eidx, shf, rb, semb, aes, ws, out, N, E, K);
}

// Round 3
// 122.129 us; speedup vs baseline: 1.2475x; 1.0900x over previous
//
#include <hip/hip_runtime.h>

#define NSPEC  3
#define EMBEDD 16
#define KMAX   32
#define RCUT   5.0f
#define PADR   36   // padded row stride (floats) for phiT/tT

// triu_indices(8) row-major
__constant__ int TUN[36] = {0,0,0,0,0,0,0,0, 1,1,1,1,1,1,1, 2,2,2,2,2,2, 3,3,3,3,3, 4,4,4,4, 5,5,5, 6,6, 7};
__constant__ int TUM[36] = {0,1,2,3,4,5,6,7, 1,2,3,4,5,6,7, 2,3,4,5,6,7, 3,4,5,6,7, 4,5,6,7, 5,6,7, 6,7, 7};

// ws layout (from magpot_setup):
//   [0..79]    wstruct[16+t]/sscale[t]
//   [80..330]  wmag[16+t]/mscale[t]
//   [331]      bstruct+bmag - sum_t w*shift/scale
//   [332..347] wstruct[l]+wmag[l]

// ---- DPP helpers (VALU-only cross-lane; no DS pipe) ----
template<int CTRL, int RMASK, bool BC>
__device__ __forceinline__ float dpp_mov0(float x) {
    // old = 0: masked-off / OOB lanes contribute 0
    return __int_as_float(__builtin_amdgcn_update_dpp(
        0, __float_as_int(x), CTRL, RMASK, 0xF, BC));
}
// inclusive prefix sum within each 32-lane half (rows of 16 + bcast15 into rows 1,3)
__device__ __forceinline__ float prefix32(float x) {
    x += dpp_mov0<0x111, 0xF, true >(x);   // row_shr:1
    x += dpp_mov0<0x112, 0xF, true >(x);   // row_shr:2
    x += dpp_mov0<0x114, 0xF, true >(x);   // row_shr:4
    x += dpp_mov0<0x118, 0xF, true >(x);   // row_shr:8
    x += dpp_mov0<0x142, 0xA, false>(x);   // row_bcast15 -> rows 1,3 only
    return x;
}
__device__ __forceinline__ float swz_xor16(float x) {
    return __int_as_float(__builtin_amdgcn_ds_swizzle(__float_as_int(x), 0x401F));
}
// reduce over lane bits 3,4 (k4): result = total in all lanes of the 32-half group-of-8
__device__ __forceinline__ float red_k4(float x) {
    x += dpp_mov0<0x128, 0xF, true>(x);    // row_ror:8 == xor 8
    x += swz_xor16(x);                     // xor 16
    return x;
}
// full 32-half sum (all lanes get total)
__device__ __forceinline__ float red32(float x) {
    x += dpp_mov0<0x121, 0xF, true>(x);    // row_ror:1
    x += dpp_mov0<0x122, 0xF, true>(x);    // row_ror:2
    x += dpp_mov0<0x124, 0xF, true>(x);    // row_ror:4
    x += dpp_mov0<0x128, 0xF, true>(x);    // row_ror:8
    x += swz_xor16(x);
    return x;
}

struct __align__(16) AtomLds {
    float phiT[8 * PADR];            // phiT[n*PADR + a]
    float tT[8 * PADR];              // tT[m*PADR + a]
    float rhx[KMAX], rhy[KMAX], rhz[KMAX];
    float mdx[KMAX], mdy[KMAX], mdz[KMAX];
    float uj[KMAX];
    float P[24], Q[48], M[24], W[24], mQ[24];
};  // 944 floats = 3776 B

__global__ __launch_bounds__(256)
void magpot_setup(const float* __restrict__ sshift, const float* __restrict__ sscale,
                  const float* __restrict__ mshift, const float* __restrict__ mscale,
                  const float* __restrict__ wstruct, const float* __restrict__ bstruct,
                  const float* __restrict__ wmag, const float* __restrict__ bmag,
                  float* __restrict__ ws)
{
    __shared__ float red[4];
    const int t = threadIdx.x;
    float c = 0.0f;
    for (int idx = t; idx < 80; idx += 256) {
        const float w = wstruct[16 + idx] / sscale[idx];
        ws[idx] = w;
        c += w * sshift[idx];
    }
    for (int idx = t; idx < 251; idx += 256) {
        const float w = wmag[16 + idx] / mscale[idx];
        ws[80 + idx] = w;
        c += w * mshift[idx];
    }
    if (t < EMBEDD) ws[332 + t] = wstruct[t] + wmag[t];
    #pragma unroll
    for (int d = 1; d <= 32; d <<= 1) c += __shfl_xor(c, d, 64);
    if ((t & 63) == 0) red[t >> 6] = c;
    __syncthreads();
    if (t == 0) ws[331] = bstruct[0] + bmag[0] - (red[0] + red[1] + red[2] + red[3]);
}

__global__ __launch_bounds__(256)
void magpot_main(const float* __restrict__ pos,
                 const int*   __restrict__ species,
                 const float* __restrict__ mag,
                 const int*   __restrict__ eidx,
                 const float* __restrict__ shifts,
                 const float* __restrict__ rb,
                 const float* __restrict__ semb,
                 const float* __restrict__ aes,
                 const float* __restrict__ ws,
                 float* __restrict__ out,
                 int N, int E, int K)
{
    __shared__ AtomLds lds[8];

    const int lane64 = threadIdx.x & 63;
    const int wv     = threadIdx.x >> 6;   // wave in block (0..3)
    const int h      = lane64 >> 5;        // half (atom within wave)
    const int s      = lane64 & 31;        // sub-lane within half
    const int ea     = 31 - s;             // edge index (REVERSED: suffix scan -> DPP prefix)
    const int i      = blockIdx.x * 8 + wv * 2 + h;
    const bool valid = (i < N);
    const int isafe  = valid ? i : 0;
    AtomLds& L = lds[wv * 2 + h];

    const float* wm = ws + 80;

    // ---- atom-level quantities (broadcast within each half) ----
    const float pix = pos[3*isafe+0], piy = pos[3*isafe+1], piz = pos[3*isafe+2];
    const int   spi = species[isafe];
    const float mgx = mag[3*isafe+0], mgy = mag[3*isafe+1], mgz = mag[3*isafe+2];
    const float u_i = mgx*mgx + mgy*mgy + mgz*mgz;
    const float mn_i = sqrtf(u_i);
    const float mi_inv = (mn_i > 1e-8f) ? (1.0f / mn_i) : 0.0f;
    const float mix = mgx*mi_inv, miy = mgy*mi_inv, miz = mgz*mi_inv;

    // ---- phase 1: per-edge (this lane owns edge ea of atom i) ----
    float phi[8];
    float rx = 0.0f, ry = 0.0f, rz = 0.0f;
    #pragma unroll
    for (int n = 0; n < 8; ++n) phi[n] = 0.0f;

    if (ea < K) {
        const int e = isafe * K + ea;
        const int j = eidx[E + e];
        rx = pos[3*j+0] - pix + shifts[3*e+0];
        ry = pos[3*j+1] - piy + shifts[3*e+1];
        rz = pos[3*j+2] - piz + shifts[3*e+2];
        const float dist = sqrtf(rx*rx + ry*ry + rz*rz);
        // cos(pi*d/5) = cos(2*pi * d/10); v_cos_f32 takes revolutions
        const float fc = (dist < RCUT)
            ? (0.5f * __builtin_amdgcn_cosf(dist * 0.1f) + 0.5f)
            : 0.0f;
        const float xr = dist * (1.0f/RCUT);
        const float x  = 2.0f * xr * xr - 1.0f;
        float f[8];
        {
            float Tm2 = 1.0f, Tm1 = x;
            f[0] = 0.5f * (Tm2 + 1.0f) * fc;
            f[1] = 0.5f * (Tm1 + 1.0f) * fc;
            #pragma unroll
            for (int k = 2; k < 8; ++k) {
                const float T = 2.0f * x * Tm1 - Tm2;
                Tm2 = Tm1; Tm1 = T;
                f[k] = 0.5f * (T + 1.0f) * fc;
            }
        }
        const int spj = species[j];
        const float4* rb4 = (const float4*)(rb + (spi * NSPEC + spj) * 64);
        #pragma unroll
        for (int n = 0; n < 8; ++n) {
            const float4 r0 = rb4[n*2+0];
            const float4 r1 = rb4[n*2+1];
            const float ph = r0.x*f[0] + r0.y*f[1] + r0.z*f[2] + r0.w*f[3]
                           + r1.x*f[4] + r1.y*f[5] + r1.z*f[6] + r1.w*f[7];
            phi[n] = ph;
            L.phiT[n*PADR + ea] = ph;
        }
        const float dinv = 1.0f / fmaxf(dist, 1e-8f);
        L.rhx[ea] = rx * dinv;
        L.rhy[ea] = ry * dinv;
        L.rhz[ea] = rz * dinv;
        const float mjx = mag[3*j+0], mjy = mag[3*j+1], mjz = mag[3*j+2];
        const float uj = mjx*mjx + mjy*mjy + mjz*mjz;
        const float mnj = sqrtf(uj);
        const float mjinv = (mnj > 1e-8f) ? (1.0f / mnj) : 0.0f;
        L.mdx[ea] = mjx * mjinv;
        L.mdy[ea] = mjy * mjinv;
        L.mdz[ea] = mjz * mjinv;
        L.uj[ea] = uj;
    } else {
        #pragma unroll
        for (int n = 0; n < 8; ++n) L.phiT[n*PADR + ea] = 0.0f;
        L.rhx[ea] = 0.0f; L.rhy[ea] = 0.0f; L.rhz[ea] = 0.0f;
        L.mdx[ea] = 0.0f; L.mdy[ea] = 0.0f; L.mdz[ea] = 0.0f;
        L.uj[ea] = 0.0f;
    }
    __syncthreads();

    float p = 0.0f;   // fused weighted-descriptor accumulator

    // ---- phase 2: segment sums. s = k4*8+n; 8 contiguous edges per lane, DPP-reduce over k4 ----
    {
        const int k4 = s >> 3;
        const int n  = s & 7;
        const float4* phR = (const float4*)&L.phiT[n*PADR + k4*8];
        const float4* hxR = (const float4*)&L.rhx[k4*8];
        const float4* hyR = (const float4*)&L.rhy[k4*8];
        const float4* hzR = (const float4*)&L.rhz[k4*8];
        const float4* dxR = (const float4*)&L.mdx[k4*8];
        const float4* dyR = (const float4*)&L.mdy[k4*8];
        const float4* dzR = (const float4*)&L.mdz[k4*8];
        const float4* ujR = (const float4*)&L.uj[k4*8];

        float a_dr = 0.0f;
        float aP0 = 0.0f, aP1 = 0.0f, aP2 = 0.0f;
        float aQ0 = 0.0f, aQ1 = 0.0f, aQ2 = 0.0f, aQ3 = 0.0f, aQ4 = 0.0f, aQ5 = 0.0f;
        float aM0 = 0.0f, aM1 = 0.0f, aM2 = 0.0f;
        float a_nb = 0.0f;
        float aW0 = 0.0f, aW1 = 0.0f, aW2 = 0.0f;

        auto acc = [&](float ph, float hx, float hy, float hz,
                       float dx, float dy, float dz, float uj) {
            a_dr += ph;
            aP0 += ph*hx; aP1 += ph*hy; aP2 += ph*hz;
            aQ0 += ph*(hx*hx - (1.0f/3.0f));
            aQ1 += ph*(hx*hy);
            aQ2 += ph*(hx*hz);
            aQ3 += ph*(hy*hy - (1.0f/3.0f));
            aQ4 += ph*(hy*hz);
            aQ5 += ph*(hz*hz - (1.0f/3.0f));
            aM0 += ph*dx; aM1 += ph*dy; aM2 += ph*dz;
            const float pu = ph*uj;
            a_nb += pu;
            aW0 += pu*dx; aW1 += pu*dy; aW2 += pu*dz;
        };
        #pragma unroll
        for (int q = 0; q < 2; ++q) {
            const float4 ph4 = phR[q], hx4 = hxR[q], hy4 = hyR[q], hz4 = hzR[q];
            const float4 dx4 = dxR[q], dy4 = dyR[q], dz4 = dzR[q], uj4 = ujR[q];
            acc(ph4.x, hx4.x, hy4.x, hz4.x, dx4.x, dy4.x, dz4.x, uj4.x);
            acc(ph4.y, hx4.y, hy4.y, hz4.y, dx4.y, dy4.y, dz4.y, uj4.y);
            acc(ph4.z, hx4.z, hy4.z, hz4.z, dx4.z, dy4.z, dz4.z, uj4.z);
            acc(ph4.w, hx4.w, hy4.w, hz4.w, dx4.w, dy4.w, dz4.w, uj4.w);
        }
        a_dr = red_k4(a_dr);
        aP0 = red_k4(aP0); aP1 = red_k4(aP1); aP2 = red_k4(aP2);
        aQ0 = red_k4(aQ0); aQ1 = red_k4(aQ1); aQ2 = red_k4(aQ2);
        aQ3 = red_k4(aQ3); aQ4 = red_k4(aQ4); aQ5 = red_k4(aQ5);
        aM0 = red_k4(aM0); aM1 = red_k4(aM1); aM2 = red_k4(aM2);
        a_nb = red_k4(a_nb);
        aW0 = red_k4(aW0); aW1 = red_k4(aW1); aW2 = red_k4(aW2);

        if (k4 == 0) {
            L.P[n*3+0] = aP0; L.P[n*3+1] = aP1; L.P[n*3+2] = aP2;
            L.Q[n*6+0] = aQ0; L.Q[n*6+1] = aQ1; L.Q[n*6+2] = aQ2;
            L.Q[n*6+3] = aQ3; L.Q[n*6+4] = aQ4; L.Q[n*6+5] = aQ5;
            L.M[n*3+0] = aM0; L.M[n*3+1] = aM1; L.M[n*3+2] = aM2;
            L.W[n*3+0] = aW0; L.W[n*3+1] = aW1; L.W[n*3+2] = aW2;
            p += a_dr * ws[n];          // d_radial
            p += a_nb * wm[227 + n];    // d_nbr_amp
        }
        if (s == 8) {                   // d_amp
            const float u2 = u_i * u_i;
            p += u_i * wm[0] + u2 * wm[1] + u2 * u_i * wm[2];
        }
        if (s < EMBEDD)                 // embedding term
            p += semb[spi * EMBEDD + s] * ws[332 + s];
    }
    __syncthreads();

    // ---- phase 3a: DMI via DPP prefix scan (edge-suffix in reversed mapping), 2 chunks of 4 m ----
    #pragma unroll
    for (int c = 0; c < 2; ++c) {
        float wxv[4], wyv[4], wzv[4];
        #pragma unroll
        for (int mm = 0; mm < 4; ++mm) {
            const int m = c*4 + mm;
            const float Mx = L.M[m*3+0], My = L.M[m*3+1], Mz = L.M[m*3+2];
            wxv[mm] = miy*Mz - miz*My;   // m_i x M[m]
            wyv[mm] = miz*Mx - mix*Mz;
            wzv[mm] = mix*My - miy*Mx;
        }
        #pragma unroll
        for (int mm = 0; mm < 4; ++mm) {
            const int m = c*4 + mm;
            const float vx = phi[m] * rx;
            const float vy = phi[m] * ry;
            const float vz = phi[m] * rz;
            const float Sx = prefix32(vx) - vx;   // exclusive: sum over edges b > ea
            const float Sy = prefix32(vy) - vy;
            const float Sz = prefix32(vz) - vz;
            const float cx = ry*Sz - rz*Sy;       // r_a x S
            const float cy = rz*Sx - rx*Sz;
            const float cz = rx*Sy - ry*Sx;
            L.tT[m*PADR + ea] = cx*wxv[mm] + cy*wyv[mm] + cz*wzv[mm];
        }
    }
    __syncthreads();

    // ---- phase 3b: d_dmi[n][m] = sum_a phiT[n][a] * tT[m][a]; lane does (n, 2c), (n, 2c+1) ----
    {
        const int n  = s >> 2;
        const int mb = (s & 3) << 1;
        const float4* phR = (const float4*)&L.phiT[n*PADR];
        const float4* t0R = (const float4*)&L.tT[mb*PADR];
        const float4* t1R = (const float4*)&L.tT[(mb+1)*PADR];
        float d0 = 0.0f, d1 = 0.0f;
        #pragma unroll
        for (int q = 0; q < 8; ++q) {
            const float4 pv = phR[q];
            const float4 t0 = t0R[q];
            const float4 t1 = t1R[q];
            d0 += pv.x*t0.x + pv.y*t0.y + pv.z*t0.z + pv.w*t0.w;
            d1 += pv.x*t1.x + pv.y*t1.y + pv.z*t1.z + pv.w*t1.w;
        }
        const int i0 = n*8 + mb;
        p += d0 * wm[83 + i0]     + (u_i * d0) * wm[163 + i0];
        p += d1 * wm[83 + i0 + 1] + (u_i * d1) * wm[163 + i0 + 1];
    }

    // ---- phase 4a: per-n magnetic descriptors (lanes s<8) ----
    if (s < 8) {
        const int n = s;
        const float Mx = L.M[n*3+0], My = L.M[n*3+1], Mz = L.M[n*3+2];
        const float diso = mix*Mx + miy*My + miz*Mz;
        const float q0 = L.Q[n*6+0], q1 = L.Q[n*6+1], q2 = L.Q[n*6+2];
        const float q3 = L.Q[n*6+3], q4 = L.Q[n*6+4], q5 = L.Q[n*6+5];
        const float dsia = q0*mix*mix + q3*miy*miy + q5*miz*miz
                         + 2.0f*(q1*mix*miy + q2*mix*miz + q4*miy*miz);
        L.mQ[n*3+0] = q0*mix + q1*miy + q2*miz;
        L.mQ[n*3+1] = q1*mix + q3*miy + q4*miz;
        L.mQ[n*3+2] = q2*mix + q4*miy + q5*miz;
        const float wx = L.W[n*3+0], wy = L.W[n*3+1], wz = L.W[n*3+2];
        const float dnex = mix*wx + miy*wy + miz*wz;
        p += diso * wm[3 + n]  + dsia * wm[11 + n]  + dnex * wm[235 + n]
           + u_i * (diso * wm[147 + n] + dsia * wm[155 + n] + dnex * wm[243 + n]);
    }
    __syncthreads();

    // ---- phase 4b: d_sae (64) + PP/QQ upper triangles (36 each) ----
    {
        #pragma unroll
        for (int t2 = 0; t2 < 2; ++t2) {
            const int idx = s + t2*32;
            const int m4 = idx >> 3, n4 = idx & 7;
            const float sae = L.mQ[m4*3+0]*L.M[n4*3+0]
                            + L.mQ[m4*3+1]*L.M[n4*3+1]
                            + L.mQ[m4*3+2]*L.M[n4*3+2];
            p += sae * wm[19 + idx];
        }
        #pragma unroll
        for (int t2 = 0; t2 < 2; ++t2) {
            const int idx = s + t2*32;
            if (idx < 36) {
                const int a = TUN[idx], b = TUM[idx];
                const float pp = L.P[a*3+0]*L.P[b*3+0] + L.P[a*3+1]*L.P[b*3+1] + L.P[a*3+2]*L.P[b*3+2];
                const float qq = L.Q[a*6+0]*L.Q[b*6+0] + L.Q[a*6+3]*L.Q[b*6+3] + L.Q[a*6+5]*L.Q[b*6+5]
                       + 2.0f*(L.Q[a*6+1]*L.Q[b*6+1] + L.Q[a*6+2]*L.Q[b*6+2] + L.Q[a*6+4]*L.Q[b*6+4]);
                p += pp * ws[8 + idx] + qq * ws[44 + idx];
            }
        }
    }

    // ---- final: reduce p within each 32-half, lane 0 writes ----
    p = red32(p);
    if (s == 0 && valid)
        out[i] = p + ws[331] + aes[spi];
}

extern "C" void kernel_launch(void* const* d_in, const int* in_sizes, int n_in,
                              void* d_out, int out_size, void* d_ws, size_t ws_size,
                              hipStream_t stream) {
    const float* pos     = (const float*)d_in[0];
    const int*   spc     = (const int*)  d_in[1];
    const float* mg      = (const float*)d_in[2];
    const int*   eidx    = (const int*)  d_in[3];
    const float* shf     = (const float*)d_in[4];
    const float* rb      = (const float*)d_in[5];
    const float* semb    = (const float*)d_in[6];
    const float* sshift  = (const float*)d_in[7];
    const float* sscale  = (const float*)d_in[8];
    const float* mshift  = (const float*)d_in[9];
    const float* mscale  = (const float*)d_in[10];
    const float* aes     = (const float*)d_in[11];
    const float* wstruct = (const float*)d_in[12];
    const float* bstruct = (const float*)d_in[13];
    const float* wmag    = (const float*)d_in[14];
    const float* bmag    = (const float*)d_in[15];
    float* out = (float*)d_out;
    float* ws  = (float*)d_ws;

    const int N = in_sizes[1];
    const int E = in_sizes[3] / 2;
    const int K = E / N;

    hipLaunchKernelGGL(magpot_setup, dim3(1), dim3(256), 0, stream,
                       sshift, sscale, mshift, mscale, wstruct, bstruct, wmag, bmag, ws);
    hipLaunchKernelGGL(magpot_main, dim3((N + 7) / 8), dim3(256), 0, stream,
                       pos, spc, mg, eidx, shf, rb, semb, aes, ws, out, N, E, K);
}

// Round 4
// 121.349 us; speedup vs baseline: 1.2555x; 1.0064x over previous
//
#include <hip/hip_runtime.h>

#define NSPEC  3
#define EMBEDD 16
#define KMAX   32
#define RCUT   5.0f
#define PADR   36   // padded row stride (floats) for phiT

// triu_indices(8) row-major
__constant__ int TUN[36] = {0,0,0,0,0,0,0,0, 1,1,1,1,1,1,1, 2,2,2,2,2,2, 3,3,3,3,3, 4,4,4,4, 5,5,5, 6,6, 7};
__constant__ int TUM[36] = {0,1,2,3,4,5,6,7, 1,2,3,4,5,6,7, 2,3,4,5,6,7, 3,4,5,6,7, 4,5,6,7, 5,6,7, 6,7, 7};

// ws layout (from magpot_setup):
//   [0..79]    wstruct[16+t]/sscale[t]
//   [80..330]  wmag[16+t]/mscale[t]
//   [331]      bstruct+bmag - sum_t w*shift/scale
//   [332..347] wstruct[l]+wmag[l]

// ---- DPP helpers (VALU-only cross-lane; no DS pipe except xor16 swizzle) ----
template<int CTRL, int RMASK, bool BC>
__device__ __forceinline__ float dpp_mov0(float x) {
    return __int_as_float(__builtin_amdgcn_update_dpp(
        0, __float_as_int(x), CTRL, RMASK, 0xF, BC));
}
__device__ __forceinline__ float prefix32(float x) {
    x += dpp_mov0<0x111, 0xF, true >(x);   // row_shr:1
    x += dpp_mov0<0x112, 0xF, true >(x);   // row_shr:2
    x += dpp_mov0<0x114, 0xF, true >(x);   // row_shr:4
    x += dpp_mov0<0x118, 0xF, true >(x);   // row_shr:8
    x += dpp_mov0<0x142, 0xA, false>(x);   // row_bcast15 -> rows 1,3
    return x;
}
__device__ __forceinline__ float swz_xor16(float x) {
    return __int_as_float(__builtin_amdgcn_ds_swizzle(__float_as_int(x), 0x401F));
}
__device__ __forceinline__ float red_k4(float x) {   // reduce lane bits 3,4
    x += dpp_mov0<0x128, 0xF, true>(x);    // row_ror:8 == xor 8
    x += swz_xor16(x);                     // xor 16
    return x;
}
__device__ __forceinline__ float red32(float x) {    // full 32-half sum
    x += dpp_mov0<0x121, 0xF, true>(x);
    x += dpp_mov0<0x122, 0xF, true>(x);
    x += dpp_mov0<0x124, 0xF, true>(x);
    x += dpp_mov0<0x128, 0xF, true>(x);
    x += swz_xor16(x);
    return x;
}

// Wave-local LDS fence: all AtomLds traffic is intra-wave (each 32-half owns its
// atom), so no __syncthreads is needed anywhere — just drain the DS queue and
// stop the compiler from reordering LDS ops across this point.
__device__ __forceinline__ void lds_fence() {
    asm volatile("s_waitcnt lgkmcnt(0)" ::: "memory");
}

struct __align__(16) AtomLds {
    float phiT[8 * PADR];   // 288: phiT[n*PADR + a]
    // overlay: {rhx,rhy,rhz,mdx,mdy,mdz,uj}[32] (phase 1-2)  <->  tT[m*32+a] (phase 3)
    float edge[256];
    float P[24], Q[48], M[24], W[24], mQ[24];
};  // 688 floats = 2752 B

__global__ __launch_bounds__(256)
void magpot_setup(const float* __restrict__ sshift, const float* __restrict__ sscale,
                  const float* __restrict__ mshift, const float* __restrict__ mscale,
                  const float* __restrict__ wstruct, const float* __restrict__ bstruct,
                  const float* __restrict__ wmag, const float* __restrict__ bmag,
                  float* __restrict__ ws)
{
    __shared__ float red[4];
    const int t = threadIdx.x;
    float c = 0.0f;
    for (int idx = t; idx < 80; idx += 256) {
        const float w = wstruct[16 + idx] / sscale[idx];
        ws[idx] = w;
        c += w * sshift[idx];
    }
    for (int idx = t; idx < 251; idx += 256) {
        const float w = wmag[16 + idx] / mscale[idx];
        ws[80 + idx] = w;
        c += w * mshift[idx];
    }
    if (t < EMBEDD) ws[332 + t] = wstruct[t] + wmag[t];
    #pragma unroll
    for (int d = 1; d <= 32; d <<= 1) c += __shfl_xor(c, d, 64);
    if ((t & 63) == 0) red[t >> 6] = c;
    __syncthreads();
    if (t == 0) ws[331] = bstruct[0] + bmag[0] - (red[0] + red[1] + red[2] + red[3]);
}

__global__ __launch_bounds__(256)
void magpot_main(const float* __restrict__ pos,
                 const int*   __restrict__ species,
                 const float* __restrict__ mag,
                 const int*   __restrict__ eidx,
                 const float* __restrict__ shifts,
                 const float* __restrict__ rb,
                 const float* __restrict__ semb,
                 const float* __restrict__ aes,
                 const float* __restrict__ ws,
                 float* __restrict__ out,
                 int N, int E, int K)
{
    __shared__ AtomLds lds[8];

    const int lane64 = threadIdx.x & 63;
    const int wv     = threadIdx.x >> 6;
    const int h      = lane64 >> 5;        // half (atom within wave)
    const int s      = lane64 & 31;
    const int ea     = 31 - s;             // edge index (reversed: suffix -> DPP prefix)
    const int i      = blockIdx.x * 8 + wv * 2 + h;
    const bool valid = (i < N);
    const int isafe  = valid ? i : 0;
    AtomLds& L = lds[wv * 2 + h];
    float* const rhx = L.edge +   0;
    float* const rhy = L.edge +  32;
    float* const rhz = L.edge +  64;
    float* const mdx = L.edge +  96;
    float* const mdy = L.edge + 128;
    float* const mdz = L.edge + 160;
    float* const uja = L.edge + 192;
    float* const tT  = L.edge;             // tT[m*32 + a], overlays the above

    const float* wm = ws + 80;

    // ---- atom-level quantities (broadcast within each half) ----
    const float pix = pos[3*isafe+0], piy = pos[3*isafe+1], piz = pos[3*isafe+2];
    const int   spi = species[isafe];
    const float mgx = mag[3*isafe+0], mgy = mag[3*isafe+1], mgz = mag[3*isafe+2];
    const float u_i = mgx*mgx + mgy*mgy + mgz*mgz;
    const float mn_i = sqrtf(u_i);
    const float mi_inv = (mn_i > 1e-8f) ? (1.0f / mn_i) : 0.0f;
    const float mix = mgx*mi_inv, miy = mgy*mi_inv, miz = mgz*mi_inv;

    // ---- phase 1: per-edge (this lane owns edge ea of atom i) ----
    float phi[8];
    float rx = 0.0f, ry = 0.0f, rz = 0.0f;
    #pragma unroll
    for (int n = 0; n < 8; ++n) phi[n] = 0.0f;

    if (ea < K) {
        const int e = isafe * K + ea;
        const int j = eidx[E + e];
        rx = pos[3*j+0] - pix + shifts[3*e+0];
        ry = pos[3*j+1] - piy + shifts[3*e+1];
        rz = pos[3*j+2] - piz + shifts[3*e+2];
        const float dist = sqrtf(rx*rx + ry*ry + rz*rz);
        // cos(pi*d/5) = cos(2*pi*(d/10)); v_cos_f32 takes revolutions
        const float fc = (dist < RCUT)
            ? (0.5f * __builtin_amdgcn_cosf(dist * 0.1f) + 0.5f)
            : 0.0f;
        const float xr = dist * (1.0f/RCUT);
        const float x  = 2.0f * xr * xr - 1.0f;
        float f[8];
        {
            float Tm2 = 1.0f, Tm1 = x;
            f[0] = 0.5f * (Tm2 + 1.0f) * fc;
            f[1] = 0.5f * (Tm1 + 1.0f) * fc;
            #pragma unroll
            for (int k = 2; k < 8; ++k) {
                const float T = 2.0f * x * Tm1 - Tm2;
                Tm2 = Tm1; Tm1 = T;
                f[k] = 0.5f * (T + 1.0f) * fc;
            }
        }
        const int spj = species[j];
        const float4* rb4 = (const float4*)(rb + (spi * NSPEC + spj) * 64);
        #pragma unroll
        for (int n = 0; n < 8; ++n) {
            const float4 r0 = rb4[n*2+0];
            const float4 r1 = rb4[n*2+1];
            const float ph = r0.x*f[0] + r0.y*f[1] + r0.z*f[2] + r0.w*f[3]
                           + r1.x*f[4] + r1.y*f[5] + r1.z*f[6] + r1.w*f[7];
            phi[n] = ph;
            L.phiT[n*PADR + ea] = ph;
        }
        const float dinv = 1.0f / fmaxf(dist, 1e-8f);
        rhx[ea] = rx * dinv;
        rhy[ea] = ry * dinv;
        rhz[ea] = rz * dinv;
        const float mjx = mag[3*j+0], mjy = mag[3*j+1], mjz = mag[3*j+2];
        const float uj = mjx*mjx + mjy*mjy + mjz*mjz;
        const float mnj = sqrtf(uj);
        const float mjinv = (mnj > 1e-8f) ? (1.0f / mnj) : 0.0f;
        mdx[ea] = mjx * mjinv;
        mdy[ea] = mjy * mjinv;
        mdz[ea] = mjz * mjinv;
        uja[ea] = uj;
    } else {
        #pragma unroll
        for (int n = 0; n < 8; ++n) L.phiT[n*PADR + ea] = 0.0f;
        rhx[ea] = 0.0f; rhy[ea] = 0.0f; rhz[ea] = 0.0f;
        mdx[ea] = 0.0f; mdy[ea] = 0.0f; mdz[ea] = 0.0f;
        uja[ea] = 0.0f;
    }
    lds_fence();   // phase-1 stores -> phase-2 reads (intra-wave)

    float p = 0.0f;   // fused weighted-descriptor accumulator

    // ---- phase 2: segment sums. s = k4*8+n; 8 contiguous edges/lane, DPP-reduce over k4 ----
    {
        const int k4 = s >> 3;
        const int n  = s & 7;
        const float4* phR = (const float4*)&L.phiT[n*PADR + k4*8];
        const float4* hxR = (const float4*)&rhx[k4*8];
        const float4* hyR = (const float4*)&rhy[k4*8];
        const float4* hzR = (const float4*)&rhz[k4*8];
        const float4* dxR = (const float4*)&mdx[k4*8];
        const float4* dyR = (const float4*)&mdy[k4*8];
        const float4* dzR = (const float4*)&mdz[k4*8];
        const float4* ujR = (const float4*)&uja[k4*8];

        float a_dr = 0.0f;
        float aP0 = 0.0f, aP1 = 0.0f, aP2 = 0.0f;
        float aQ0 = 0.0f, aQ1 = 0.0f, aQ2 = 0.0f, aQ3 = 0.0f, aQ4 = 0.0f, aQ5 = 0.0f;
        float aM0 = 0.0f, aM1 = 0.0f, aM2 = 0.0f;
        float a_nb = 0.0f;
        float aW0 = 0.0f, aW1 = 0.0f, aW2 = 0.0f;

        auto acc = [&](float ph, float hx, float hy, float hz,
                       float dx, float dy, float dz, float uj) {
            a_dr += ph;
            aP0 += ph*hx; aP1 += ph*hy; aP2 += ph*hz;
            aQ0 += ph*(hx*hx - (1.0f/3.0f));
            aQ1 += ph*(hx*hy);
            aQ2 += ph*(hx*hz);
            aQ3 += ph*(hy*hy - (1.0f/3.0f));
            aQ4 += ph*(hy*hz);
            aQ5 += ph*(hz*hz - (1.0f/3.0f));
            aM0 += ph*dx; aM1 += ph*dy; aM2 += ph*dz;
            const float pu = ph*uj;
            a_nb += pu;
            aW0 += pu*dx; aW1 += pu*dy; aW2 += pu*dz;
        };
        #pragma unroll
        for (int q = 0; q < 2; ++q) {
            const float4 ph4 = phR[q], hx4 = hxR[q], hy4 = hyR[q], hz4 = hzR[q];
            const float4 dx4 = dxR[q], dy4 = dyR[q], dz4 = dzR[q], uj4 = ujR[q];
            acc(ph4.x, hx4.x, hy4.x, hz4.x, dx4.x, dy4.x, dz4.x, uj4.x);
            acc(ph4.y, hx4.y, hy4.y, hz4.y, dx4.y, dy4.y, dz4.y, uj4.y);
            acc(ph4.z, hx4.z, hy4.z, hz4.z, dx4.z, dy4.z, dz4.z, uj4.z);
            acc(ph4.w, hx4.w, hy4.w, hz4.w, dx4.w, dy4.w, dz4.w, uj4.w);
        }
        a_dr = red_k4(a_dr);
        aP0 = red_k4(aP0); aP1 = red_k4(aP1); aP2 = red_k4(aP2);
        aQ0 = red_k4(aQ0); aQ1 = red_k4(aQ1); aQ2 = red_k4(aQ2);
        aQ3 = red_k4(aQ3); aQ4 = red_k4(aQ4); aQ5 = red_k4(aQ5);
        aM0 = red_k4(aM0); aM1 = red_k4(aM1); aM2 = red_k4(aM2);
        a_nb = red_k4(a_nb);
        aW0 = red_k4(aW0); aW1 = red_k4(aW1); aW2 = red_k4(aW2);

        if (k4 == 0) {
            L.P[n*3+0] = aP0; L.P[n*3+1] = aP1; L.P[n*3+2] = aP2;
            L.Q[n*6+0] = aQ0; L.Q[n*6+1] = aQ1; L.Q[n*6+2] = aQ2;
            L.Q[n*6+3] = aQ3; L.Q[n*6+4] = aQ4; L.Q[n*6+5] = aQ5;
            L.M[n*3+0] = aM0; L.M[n*3+1] = aM1; L.M[n*3+2] = aM2;
            L.W[n*3+0] = aW0; L.W[n*3+1] = aW1; L.W[n*3+2] = aW2;
            p += a_dr * ws[n];          // d_radial
            p += a_nb * wm[227 + n];    // d_nbr_amp
        }
        if (s == 8) {                   // d_amp
            const float u2 = u_i * u_i;
            p += u_i * wm[0] + u2 * wm[1] + u2 * u_i * wm[2];
        }
        if (s < EMBEDD)                 // embedding term
            p += semb[spi * EMBEDD + s] * ws[332 + s];
    }
    lds_fence();   // phase-2 reads of edge[] done + P/Q/M/W stores -> 3a (WAR on edge[], RAW on M)

    // ---- phase 3a: DMI via DPP prefix scan; tT[m*32+a] overlays the dead edge arrays ----
    #pragma unroll
    for (int c = 0; c < 2; ++c) {
        #pragma unroll
        for (int mm = 0; mm < 4; ++mm) {
            const int m = c*4 + mm;
            const float Mx = L.M[m*3+0], My = L.M[m*3+1], Mz = L.M[m*3+2];
            const float wx = miy*Mz - miz*My;     // m_i x M[m]
            const float wy = miz*Mx - mix*Mz;
            const float wz = mix*My - miy*Mx;
            const float vx = phi[m] * rx;
            const float vy = phi[m] * ry;
            const float vz = phi[m] * rz;
            const float Sx = prefix32(vx) - vx;   // exclusive: sum over edges b > ea
            const float Sy = prefix32(vy) - vy;
            const float Sz = prefix32(vz) - vz;
            const float cx = ry*Sz - rz*Sy;       // r_a x S
            const float cy = rz*Sx - rx*Sz;
            const float cz = rx*Sy - ry*Sx;
            tT[m*32 + ea] = cx*wx + cy*wy + cz*wz;
        }
    }
    lds_fence();   // 3a stores -> 3b reads

    // ---- phase 3b: d_dmi[n][m] = sum_a phiT[n][a] * tT[m][a]; lane does (n, 2c), (n, 2c+1) ----
    {
        const int n  = s >> 2;
        const int mb = (s & 3) << 1;
        const float4* phR = (const float4*)&L.phiT[n*PADR];
        const float4* t0R = (const float4*)&tT[mb*32];
        const float4* t1R = (const float4*)&tT[(mb+1)*32];
        float d0 = 0.0f, d1 = 0.0f;
        #pragma unroll
        for (int q = 0; q < 8; ++q) {
            const float4 pv = phR[q];
            const float4 t0 = t0R[q];
            const float4 t1 = t1R[q];
            d0 += pv.x*t0.x + pv.y*t0.y + pv.z*t0.z + pv.w*t0.w;
            d1 += pv.x*t1.x + pv.y*t1.y + pv.z*t1.z + pv.w*t1.w;
        }
        const int i0 = n*8 + mb;
        p += d0 * wm[83 + i0]     + (u_i * d0) * wm[163 + i0];
        p += d1 * wm[83 + i0 + 1] + (u_i * d1) * wm[163 + i0 + 1];
    }

    // ---- phase 4a: per-n magnetic descriptors (lanes s<8) ----
    if (s < 8) {
        const int n = s;
        const float Mx = L.M[n*3+0], My = L.M[n*3+1], Mz = L.M[n*3+2];
        const float diso = mix*Mx + miy*My + miz*Mz;
        const float q0 = L.Q[n*6+0], q1 = L.Q[n*6+1], q2 = L.Q[n*6+2];
        const float q3 = L.Q[n*6+3], q4 = L.Q[n*6+4], q5 = L.Q[n*6+5];
        const float dsia = q0*mix*mix + q3*miy*miy + q5*miz*miz
                         + 2.0f*(q1*mix*miy + q2*mix*miz + q4*miy*miz);
        L.mQ[n*3+0] = q0*mix + q1*miy + q2*miz;
        L.mQ[n*3+1] = q1*mix + q3*miy + q4*miz;
        L.mQ[n*3+2] = q2*mix + q4*miy + q5*miz;
        const float wx = L.W[n*3+0], wy = L.W[n*3+1], wz = L.W[n*3+2];
        const float dnex = mix*wx + miy*wy + miz*wz;
        p += diso * wm[3 + n]  + dsia * wm[11 + n]  + dnex * wm[235 + n]
           + u_i * (diso * wm[147 + n] + dsia * wm[155 + n] + dnex * wm[243 + n]);
    }
    lds_fence();   // mQ stores -> 4b reads

    // ---- phase 4b: d_sae (64) + PP/QQ upper triangles (36 each) ----
    {
        #pragma unroll
        for (int t2 = 0; t2 < 2; ++t2) {
            const int idx = s + t2*32;
            const int m4 = idx >> 3, n4 = idx & 7;
            const float sae = L.mQ[m4*3+0]*L.M[n4*3+0]
                            + L.mQ[m4*3+1]*L.M[n4*3+1]
                            + L.mQ[m4*3+2]*L.M[n4*3+2];
            p += sae * wm[19 + idx];
        }
        #pragma unroll
        for (int t2 = 0; t2 < 2; ++t2) {
            const int idx = s + t2*32;
            if (idx < 36) {
                const int a = TUN[idx], b = TUM[idx];
                const float pp = L.P[a*3+0]*L.P[b*3+0] + L.P[a*3+1]*L.P[b*3+1] + L.P[a*3+2]*L.P[b*3+2];
                const float qq = L.Q[a*6+0]*L.Q[b*6+0] + L.Q[a*6+3]*L.Q[b*6+3] + L.Q[a*6+5]*L.Q[b*6+5]
                       + 2.0f*(L.Q[a*6+1]*L.Q[b*6+1] + L.Q[a*6+2]*L.Q[b*6+2] + L.Q[a*6+4]*L.Q[b*6+4]);
                p += pp * ws[8 + idx] + qq * ws[44 + idx];
            }
        }
    }

    // ---- final: reduce p within each 32-half, lane 0 writes ----
    p = red32(p);
    if (s == 0 && valid)
        out[i] = p + ws[331] + aes[spi];
}

extern "C" void kernel_launch(void* const* d_in, const int* in_sizes, int n_in,
                              void* d_out, int out_size, void* d_ws, size_t ws_size,
                              hipStream_t stream) {
    const float* pos     = (const float*)d_in[0];
    const int*   spc     = (const int*)  d_in[1];
    const float* mg      = (const float*)d_in[2];
    const int*   eidx    = (const int*)  d_in[3];
    const float* shf     = (const float*)d_in[4];
    const float* rb      = (const float*)d_in[5];
    const float* semb    = (const float*)d_in[6];
    const float* sshift  = (const float*)d_in[7];
    const float* sscale  = (const float*)d_in[8];
    const float* mshift  = (const float*)d_in[9];
    const float* mscale  = (const float*)d_in[10];
    const float* aes     = (const float*)d_in[11];
    const float* wstruct = (const float*)d_in[12];
    const float* bstruct = (const float*)d_in[13];
    const float* wmag    = (const float*)d_in[14];
    const float* bmag    = (const float*)d_in[15];
    float* out = (float*)d_out;
    float* ws  = (float*)d_ws;

    const int N = in_sizes[1];
    const int E = in_sizes[3] / 2;
    const int K = E / N;

    hipLaunchKernelGGL(magpot_setup, dim3(1), dim3(256), 0, stream,
                       sshift, sscale, mshift, mscale, wstruct, bstruct, wmag, bmag, ws);
    hipLaunchKernelGGL(magpot_main, dim3((N + 7) / 8), dim3(256), 0, stream,
                       pos, spc, mg, eidx, shf, rb, semb, aes, ws, out, N, E, K);
}